// Round 12
// baseline (77.866 us; speedup 1.0000x reference)
//
#include <hip/hip_runtime.h>
#include <math.h>

typedef float f32x2 __attribute__((ext_vector_type(2)));

#define NCH 96      // B*C = 32*3
#define HH 512
#define WW 512
#define OH 502      // valid output rows/cols (512 - 10)
#define STRIP 32    // output rows per block (last strip = 22, even)
#define NSTRIP 16
#define NT 256      // threads per block

struct Win { float w[11]; };

__device__ __forceinline__ f32x2 pkfma(f32x2 a, f32x2 b, f32x2 c) {
    return __builtin_elementwise_fma(a, b, c);
}
__device__ __forceinline__ f32x2 pkfmas(f32x2 a, float s, f32x2 c) {
    f32x2 sv = {s, s};
    return __builtin_elementwise_fma(a, sv, c);
}
__device__ __forceinline__ f32x2 pkmuls(f32x2 a, float s) {
    f32x2 sv = {s, s};
    return a * sv;
}

// packed SSIM for two pixels: mu1,mu2,ms,mp hold (pixelA, pixelB)
__device__ __forceinline__ float ssim_px2(f32x2 mu1, f32x2 mu2, f32x2 ms, f32x2 mp) {
    const f32x2 C1v = {1e-4f, 1e-4f};   // (0.01)^2
    const f32x2 C2v = {9e-4f, 9e-4f};   // (0.03)^2
    const f32x2 two = {2.f, 2.f};
    f32x2 mu12  = mu1 * mu2;
    f32x2 musum = pkfma(mu1, mu1, mu2 * mu2);
    f32x2 num = pkfma(two, mp - mu12, C2v) * pkfma(two, mu12, C1v);
    f32x2 den = ((ms - musum) + C2v) * (musum + C1v); // > 0 always
    float ra = __builtin_amdgcn_rcpf(den.x);
    float rb = __builtin_amdgcn_rcpf(den.y);
    return fmaf(num.x, ra, num.y * rb);
}

// packed 11-tap horizontal blur chain (taps T0..T10, scalar weights w0..w10)
#define HB(T0,T1,T2,T3,T4,T5,T6,T7,T8,T9,T10) \
  pkfmas(T10, w10, pkfmas(T9, w9, pkfmas(T8, w8, pkfmas(T7, w7, \
  pkfmas(T6, w6, pkfmas(T5, w5, pkfmas(T4, w4, pkfmas(T3, w3, \
  pkfmas(T2, w2, pkfmas(T1, w1, pkmuls(T0, w0)))))))))))

__global__ __launch_bounds__(NT, 4)
void ssim_main(const float* __restrict__ X, const float* __restrict__ Y,
               float* __restrict__ partial, Win win) {
    // Single buffer (16.6 KB); write/read separated by the two barriers.
    // M = (mu1_e, mu2_e, mu1_o, mu2_o); S = (ms_e, mp_e, ms_o, mp_o)
    __shared__ float4 Mb[2][256];   // [row01][colpair]
    __shared__ float4 Sb[2][256];
    __shared__ float red[4];

    const int b     = blockIdx.x;
    const int ch    = b >> 4;         // / NSTRIP
    const int strip = b & 15;
    const int r0    = strip * STRIP;
    const int rows  = min(STRIP, OH - r0);   // 32 or 22 (even)
    const int t     = threadIdx.x;

    const float w0 = win.w[0], w1 = win.w[1], w2 = win.w[2], w3 = win.w[3];
    const float w4 = win.w[4], w5 = win.w[5], w6 = win.w[6], w7 = win.w[7];
    const float w8 = win.w[8], w9 = win.w[9], w10 = win.w[10];
    const f32x2 h2 = {0.5f, 0.5f};

    const size_t choff = (size_t)ch * (HH * WW);
    const float* xcol = X + choff + 2 * t;   // column-pair base (vblur phase)
    const float* ycol = Y + choff + 2 * t;

    // hblur-phase decomposition: row rr = t>>7, 4-col group g = t&127
    const int rr = t >> 7;
    const int g  = t & 127;
    const int cp = 2 * (g < 126 ? g : 125);          // clamped tap base
    const int c6 = (cp + 6 < 256) ? cp + 6 : 255;    // clamped last tap

    // 10-slot shift ring of NORMALIZED (even,odd) packed values.
    f32x2 xs[10], ys[10];
    #pragma unroll
    for (int i = 0; i < 10; ++i) {
        f32x2 xv = *(const f32x2*)(xcol + (size_t)(r0 + i) * WW);
        f32x2 yv = *(const f32x2*)(ycol + (size_t)(r0 + i) * WW);
        xs[i] = pkfma(xv, h2, h2);
        ys[i] = pkfma(yv, h2, h2);
    }
    // held raw rows r0+10, r0+11
    f32x2 hx1 = *(const f32x2*)(xcol + (size_t)(r0 + 10) * WW);
    f32x2 hy1 = *(const f32x2*)(ycol + (size_t)(r0 + 10) * WW);
    f32x2 hx2 = *(const f32x2*)(xcol + (size_t)(r0 + 11) * WW);
    f32x2 hy2 = *(const f32x2*)(ycol + (size_t)(r0 + 11) * WW);

    float acc = 0.f;

    for (int r = 0; r < rows; r += 2) {
        // normalize held rows (consume prefetch); s,p on the fly
        f32x2 n1x = pkfma(hx1, h2, h2), n1y = pkfma(hy1, h2, h2);
        f32x2 n2x = pkfma(hx2, h2, h2), n2y = pkfma(hy2, h2, h2);
        f32x2 n1s = pkfma(n1y, n1y, n1x * n1x), n1p = n1x * n1y;
        f32x2 n2s = pkfma(n2y, n2y, n2x * n2x), n2p = n2x * n2y;

        // vblur row A = r   : w[k] over ring[0..9] (rows r..r+9) + w10*n1
        //       row B = r+1 : w[k-1] over ring[1..9] + w9*n1 + w10*n2
        f32x2 uAx = pkmuls(n1x, w10), uAy = pkmuls(n1y, w10);
        f32x2 uAs = pkmuls(n1s, w10), uAp = pkmuls(n1p, w10);
        f32x2 uBx = pkfmas(n1x, w9, pkmuls(n2x, w10));
        f32x2 uBy = pkfmas(n1y, w9, pkmuls(n2y, w10));
        f32x2 uBs = pkfmas(n1s, w9, pkmuls(n2s, w10));
        f32x2 uBp = pkfmas(n1p, w9, pkmuls(n2p, w10));
        #pragma unroll
        for (int k = 0; k < 10; ++k) {
            const float wk = win.w[k];
            f32x2 qx = xs[k], qy = ys[k];
            f32x2 qs = pkfma(qy, qy, qx * qx), qp = qx * qy;   // shared by both rows
            uAx = pkfmas(qx, wk, uAx); uAy = pkfmas(qy, wk, uAy);
            uAs = pkfmas(qs, wk, uAs); uAp = pkfmas(qp, wk, uAp);
            if (k >= 1) {
                const float wk1 = win.w[k - 1];
                uBx = pkfmas(qx, wk1, uBx); uBy = pkfmas(qy, wk1, uBy);
                uBs = pkfmas(qs, wk1, uBs); uBp = pkfmas(qp, wk1, uBp);
            }
        }

        // shift ring by 2; append normalized held rows
        #pragma unroll
        for (int k = 0; k < 8; ++k) { xs[k] = xs[k + 2]; ys[k] = ys[k + 2]; }
        xs[8] = n1x; ys[8] = n1y; xs[9] = n2x; ys[9] = n2y;

        // BARRIER A: all threads done reading previous iteration's LDS data
        __syncthreads();

        Mb[0][t] = make_float4(uAx.x, uAy.x, uAx.y, uAy.y);
        Sb[0][t] = make_float4(uAs.x, uAp.x, uAs.y, uAp.y);
        Mb[1][t] = make_float4(uBx.x, uBy.x, uBx.y, uBy.y);
        Sb[1][t] = make_float4(uBs.x, uBp.x, uBs.y, uBp.y);

        // BARRIER B: writes visible
        __syncthreads();

        // prefetch AFTER the barrier: loads land during the hblur region
        {
            const int g1 = min(r0 + r + 12, HH - 1);
            const int g2 = min(r0 + r + 13, HH - 1);
            hx1 = *(const f32x2*)(xcol + (size_t)g1 * WW);
            hy1 = *(const f32x2*)(ycol + (size_t)g1 * WW);
            hx2 = *(const f32x2*)(xcol + (size_t)g2 * WW);
            hy2 = *(const f32x2*)(ycol + (size_t)g2 * WW);
        }

        // hblur + ssim: this thread covers row rr, output cols 4g..4g+3.
        // Two adjacent colpairs share taps: 7 M + 7 S reads for 4 outputs.
        {
            const float4* Mp = Mb[rr];
            const float4* Sp = Sb[rr];
            float4 m0 = Mp[cp],     m1 = Mp[cp + 1], m2 = Mp[cp + 2];
            float4 m3 = Mp[cp + 3], m4 = Mp[cp + 4], m5 = Mp[cp + 5];
            float4 m6 = Mp[c6];
            float4 s0 = Sp[cp],     s1 = Sp[cp + 1], s2 = Sp[cp + 2];
            float4 s3 = Sp[cp + 3], s4 = Sp[cp + 4], s5 = Sp[cp + 5];
            float4 s6 = Sp[c6];

            f32x2 e0m = {m0.x, m0.y}, o0m = {m0.z, m0.w};
            f32x2 e1m = {m1.x, m1.y}, o1m = {m1.z, m1.w};
            f32x2 e2m = {m2.x, m2.y}, o2m = {m2.z, m2.w};
            f32x2 e3m = {m3.x, m3.y}, o3m = {m3.z, m3.w};
            f32x2 e4m = {m4.x, m4.y}, o4m = {m4.z, m4.w};
            f32x2 e5m = {m5.x, m5.y}, o5m = {m5.z, m5.w};
            f32x2 e6m = {m6.x, m6.y}, o6m = {m6.z, m6.w};
            f32x2 e0s = {s0.x, s0.y}, o0s = {s0.z, s0.w};
            f32x2 e1s = {s1.x, s1.y}, o1s = {s1.z, s1.w};
            f32x2 e2s = {s2.x, s2.y}, o2s = {s2.z, s2.w};
            f32x2 e3s = {s3.x, s3.y}, o3s = {s3.z, s3.w};
            f32x2 e4s = {s4.x, s4.y}, o4s = {s4.z, s4.w};
            f32x2 e5s = {s5.x, s5.y}, o5s = {s5.z, s5.w};
            f32x2 e6s = {s6.x, s6.y}, o6s = {s6.z, s6.w};

            // colpair cp (cols 4g, 4g+1)
            f32x2 Am = HB(e0m,o0m,e1m,o1m,e2m,o2m,e3m,o3m,e4m,o4m,e5m);
            f32x2 As = HB(e0s,o0s,e1s,o1s,e2s,o2s,e3s,o3s,e4s,o4s,e5s);
            f32x2 Bm = HB(o0m,e1m,o1m,e2m,o2m,e3m,o3m,e4m,o4m,e5m,o5m);
            f32x2 Bs = HB(o0s,e1s,o1s,e2s,o2s,e3s,o3s,e4s,o4s,e5s,o5s);
            // colpair cp+1 (cols 4g+2, 4g+3)
            f32x2 Cm = HB(e1m,o1m,e2m,o2m,e3m,o3m,e4m,o4m,e5m,o5m,e6m);
            f32x2 Cs = HB(e1s,o1s,e2s,o2s,e3s,o3s,e4s,o4s,e5s,o5s,e6s);
            f32x2 Dm = HB(o1m,e2m,o2m,e3m,o3m,e4m,o4m,e5m,o5m,e6m,o6m);
            f32x2 Ds = HB(o1s,e2s,o2s,e3s,o3s,e4s,o4s,e5s,o5s,e6s,o6s);

            if (g <= 125) {
                f32x2 mu1 = {Am.x, Bm.x}, mu2 = {Am.y, Bm.y};
                f32x2 msv = {As.x, Bs.x}, mpv = {As.y, Bs.y};
                acc += ssim_px2(mu1, mu2, msv, mpv);
            }
            if (g <= 124) {
                f32x2 mu1 = {Cm.x, Dm.x}, mu2 = {Cm.y, Dm.y};
                f32x2 msv = {Cs.x, Ds.x}, mpv = {Cs.y, Ds.y};
                acc += ssim_px2(mu1, mu2, msv, mpv);
            }
        }
    }

    // block reduction -> one partial per block (no atomics: deterministic)
    #pragma unroll
    for (int m = 1; m < 64; m <<= 1) acc += __shfl_xor(acc, m, 64);
    __syncthreads();
    if ((t & 63) == 0) red[t >> 6] = acc;
    __syncthreads();
    if (t == 0) partial[b] = (red[0] + red[1]) + (red[2] + red[3]);
}

__global__ __launch_bounds__(128)
void ssim_final(const float* __restrict__ partial, float* __restrict__ out) {
    const int t = threadIdx.x;  // 128 threads
    float v = 0.f;
    if (t < NCH) {
        float s = 0.f;
        #pragma unroll
        for (int i = 0; i < NSTRIP; ++i) s += partial[t * NSTRIP + i];
        s *= (1.f / (502.f * 502.f));   // per-channel spatial mean
        v = fmaxf(s, 0.f);              // relu (nonnegative_ssim)
    }
    #pragma unroll
    for (int m = 1; m < 64; m <<= 1) v += __shfl_xor(v, m, 64);
    __shared__ float r2[2];
    if ((t & 63) == 0) r2[t >> 6] = v;
    __syncthreads();
    if (t == 0) out[0] = 1.f - (r2[0] + r2[1]) * (1.f / (float)NCH);
}

extern "C" void kernel_launch(void* const* d_in, const int* in_sizes, int n_in,
                              void* d_out, int out_size, void* d_ws, size_t ws_size,
                              hipStream_t stream) {
    const float* X = (const float*)d_in[0];
    const float* Y = (const float*)d_in[1];
    float* out = (float*)d_out;
    float* partial = (float*)d_ws;   // NCH*NSTRIP = 1536 floats

    Win win;
    double g[11], sum = 0.0;
    for (int i = 0; i < 11; ++i) {
        double c = (double)(i - 5);
        g[i] = exp(-(c * c) / (2.0 * 1.5 * 1.5));
        sum += g[i];
    }
    for (int i = 0; i < 11; ++i) win.w[i] = (float)(g[i] / sum);

    ssim_main<<<NCH * NSTRIP, NT, 0, stream>>>(X, Y, partial, win);
    ssim_final<<<1, 128, 0, stream>>>(partial, out);
}